// Round 1
// baseline (316.918 us; speedup 1.0000x reference)
//
#include <hip/hip_runtime.h>
#include <hip/hip_bf16.h>

typedef __hip_bfloat16 bf16;

#define N_B   4
#define LSEQ  2048
#define DM    1024
#define NH    16
#define HD    64
#define MROWS (N_B * LSEQ)   // 8192
#define TCH   64
#define NC    (LSEQ / TCH)   // 32 chunks
#define PS    72             // LDS row stride (bf16 elems) for attn kernels

typedef short bf16x8 __attribute__((ext_vector_type(8)));
typedef float f32x4  __attribute__((ext_vector_type(4)));

__device__ __forceinline__ float u2f(unsigned short u){ return __uint_as_float(((unsigned)u) << 16); }
__device__ __forceinline__ unsigned short f2u(float x){
    bf16 h = __float2bfloat16(x);
    return *reinterpret_cast<unsigned short*>(&h);
}

__device__ __forceinline__ void g2l16(const void* g, void* l) {
    __builtin_amdgcn_global_load_lds(
        (const __attribute__((address_space(1))) unsigned int*)g,
        (__attribute__((address_space(3))) unsigned int*)l, 16, 0, 0);
}

// ---------------------------------------------------------------------------
// fused fp32 -> bf16 convert for 3 tensors (blockIdx.x / per selects tensor)
__global__ __launch_bounds__(256) void cvt3_f32_bf16(
    const float* __restrict__ x0, const float* __restrict__ x1, const float* __restrict__ x2,
    bf16* __restrict__ y0, bf16* __restrict__ y1, bf16* __restrict__ y2, int per)
{
    int which = blockIdx.x / per;
    const float* x = (which == 0) ? x0 : (which == 1) ? x1 : x2;
    bf16* y = (which == 0) ? y0 : (which == 1) ? y1 : y2;
    int i = (blockIdx.x - which * per) * 256 + threadIdx.x;
    float4 v = ((const float4*)x)[i];
    ushort4 o = make_ushort4(f2u(v.x), f2u(v.y), f2u(v.z), f2u(v.w));
    ((ushort4*)y)[i] = o;
}

// fused transpose for 4 weight matrices: W [K][N] fp32 -> Wt [N][K] bf16
__global__ __launch_bounds__(256) void transpose_w4(
    const float* __restrict__ W0, const float* __restrict__ W1,
    const float* __restrict__ W2, const float* __restrict__ W3,
    bf16* __restrict__ T0, bf16* __restrict__ T1,
    bf16* __restrict__ T2, bf16* __restrict__ T3)
{
    const int z = blockIdx.z;
    const float* W = (z == 0) ? W0 : (z == 1) ? W1 : (z == 2) ? W2 : W3;
    bf16* Wt = (z == 0) ? T0 : (z == 1) ? T1 : (z == 2) ? T2 : T3;

    __shared__ unsigned short t[64][65];
    const int n0 = blockIdx.x * 64;
    const int k0 = blockIdx.y * 64;
    #pragma unroll
    for (int i = 0; i < 16; ++i) {
        int e = i * 256 + threadIdx.x;
        int r = e >> 6, c = e & 63;
        t[c][r] = f2u(W[(size_t)(k0 + r) * DM + n0 + c]);
    }
    __syncthreads();
    #pragma unroll
    for (int i = 0; i < 16; ++i) {
        int e = i * 256 + threadIdx.x;
        int r = e >> 6, c = e & 63;
        ((unsigned short*)Wt)[(size_t)(n0 + r) * DM + k0 + c] = t[r][c];
    }
}

// ---------------------------------------------------------------------------
// MFMA GEMM, up to 3 problems in one launch (blockIdx.z selects).
// C = act(A @ Bt^T + bias), act per-z via actMask bit. XOR-swizzled LDS.
// 4-deep pipelined LDS (BK=32 K-tiles), counted vmcnt (never 0 in steady
// state), ONE raw s_barrier per K-tile, setprio around the MFMA cluster.
template <typename TO>
__global__ __launch_bounds__(256, 2) void gemm_mfma3(
    const bf16* __restrict__ A0, const bf16* __restrict__ A1, const bf16* __restrict__ A2,
    const bf16* __restrict__ B0, const bf16* __restrict__ B1, const bf16* __restrict__ B2,
    const float* __restrict__ c0, const float* __restrict__ c1, const float* __restrict__ c2,
    TO* __restrict__ C0, TO* __restrict__ C1, TO* __restrict__ C2,
    int actMask, int M, int N, int K)
{
    const int z = blockIdx.z;
    const bf16* A  = (z == 0) ? A0 : (z == 1) ? A1 : A2;
    const bf16* Bt = (z == 0) ? B0 : (z == 1) ? B1 : B2;
    const float* bias = (z == 0) ? c0 : (z == 1) ? c1 : c2;
    TO* C = (z == 0) ? C0 : (z == 1) ? C1 : C2;
    const int act = (actMask >> z) & 1;

    // 4 buffers x (128 rows x 32 cols) bf16 for each of A and B = 64 KiB
    __shared__ __align__(16) short As[4 * 128 * 32];
    __shared__ __align__(16) short Bs[4 * 128 * 32];

    const int tid  = threadIdx.x;
    const int m0   = blockIdx.x * 128;
    const int n0   = blockIdx.y * 128;
    const int wave = tid >> 6;
    const int lane = tid & 63;
    const int wm   = (wave >> 1) * 64;
    const int wn   = (wave & 1) * 64;
    const int quad = lane >> 4;
    const int l16  = lane & 15;
    const int ksw  = (quad ^ (l16 & 3)) * 8;   // swizzled k-group for frag reads

    f32x4 acc[4][4] = {};

    const int NT = K >> 5;   // number of BK=32 K-tiles (32 here)

    // stage one K-tile (4 global_load_lds per wave: 2 for A, 2 for B)
    auto stage = [&](int t, int buf) {
        const int k0i = t << 5;
        short* Ad = As + buf * (128 * 32);
        short* Bd = Bs + buf * (128 * 32);
        #pragma unroll
        for (int i = 0; i < 2; ++i) {
            int e = i * 256 + tid;
            int row = e >> 2, kg = e & 3;
            int kgs = (kg ^ (row & 3)) * 8;    // store global kg at swizzled slot
            g2l16(A  + (size_t)(m0 + row) * K + k0i + kgs, Ad + e * 8);
            g2l16(Bt + (size_t)(n0 + row) * K + k0i + kgs, Bd + e * 8);
        }
    };

    auto compute = [&](int buf) {
        const short* Ab = As + buf * (128 * 32);
        const short* Bb = Bs + buf * (128 * 32);
        bf16x8 af[4], bfr[4];
        #pragma unroll
        for (int mi = 0; mi < 4; ++mi)
            af[mi] = *(const bf16x8*)&Ab[(wm + mi * 16 + l16) * 32 + ksw];
        #pragma unroll
        for (int ni = 0; ni < 4; ++ni)
            bfr[ni] = *(const bf16x8*)&Bb[(wn + ni * 16 + l16) * 32 + ksw];
        __builtin_amdgcn_s_setprio(1);
        #pragma unroll
        for (int mi = 0; mi < 4; ++mi)
            #pragma unroll
            for (int ni = 0; ni < 4; ++ni)
                acc[mi][ni] = __builtin_amdgcn_mfma_f32_16x16x32_bf16(
                    af[mi], bfr[ni], acc[mi][ni], 0, 0, 0);
        __builtin_amdgcn_s_setprio(0);
    };

    // prologue: prefetch tiles 0,1,2 (12 loads in flight per wave)
    stage(0, 0);
    stage(1, 1);
    stage(2, 2);

    for (int t = 0; t < NT; ++t) {
        // Counted wait: vmcnt retires in issue order, so leaving the 2 newest
        // tiles (8 loads) in flight guarantees tile t has fully landed.
        if (t < NT - 2)
            asm volatile("s_waitcnt vmcnt(8)" ::: "memory");
        else if (t == NT - 2)
            asm volatile("s_waitcnt vmcnt(4)" ::: "memory");
        else
            asm volatile("s_waitcnt vmcnt(0)" ::: "memory");
        // One barrier per K-tile: publishes other waves' staged slices of
        // tile t, and proves all waves finished reading buf (t-1)&3 so the
        // stage below (tile t+3 -> same buf) is WAR-safe.
        __builtin_amdgcn_s_barrier();
        __builtin_amdgcn_sched_barrier(0);
        if (t + 3 < NT) stage(t + 3, (t + 3) & 3);
        compute(t & 3);
    }

    #pragma unroll
    for (int ni = 0; ni < 4; ++ni) {
        int col = n0 + wn + ni * 16 + l16;
        float bv = bias[col];
        #pragma unroll
        for (int mi = 0; mi < 4; ++mi) {
            #pragma unroll
            for (int r = 0; r < 4; ++r) {
                int row = m0 + wm + mi * 16 + quad * 4 + r;
                float x = acc[mi][ni][r] + bv;
                if (act) x = (x > 0.f) ? (x + 1.f) : __expf(x);
                if constexpr (sizeof(TO) == 2)
                    ((bf16*)C)[(size_t)row * N + col] = __float2bfloat16(x);
                else
                    ((float*)C)[(size_t)row * N + col] = x;
            }
        }
    }
}

// ---------------------------------------------------------------------------
// Pass 1 (MFMA): chunkSB[d][k] = sum_t kp[t][d]*v[t][k] (bf16); chunkZ fp32
__global__ __launch_bounds__(256) void chunk_state(
    const bf16* __restrict__ qp, const bf16* __restrict__ kp,
    const bf16* __restrict__ v,
    bf16* __restrict__ chunkSB, float* __restrict__ chunkZ)
{
    __shared__ __align__(16) unsigned short kpT_s[64 * PS];
    __shared__ __align__(16) unsigned short vT_s [64 * PS];
    __shared__ __align__(16) unsigned short qp_s [64 * PS];
    __shared__ float red[4][64];

    const int bh = blockIdx.x;
    const int c  = blockIdx.y;
    const int n  = bh >> 4, h = bh & 15;
    const int tid = threadIdx.x;
    const size_t rowbase = (size_t)n * LSEQ + (size_t)c * TCH;

    #pragma unroll
    for (int r = 0; r < 4; ++r) {
        int q = r * 256 + tid;
        int t = q >> 4, c0 = (q & 15) * 4;
        size_t g = (rowbase + t) * DM + h * HD + c0;
        ushort4 ku = *(const ushort4*)((const unsigned short*)kp + g);
        ushort4 vu = *(const ushort4*)((const unsigned short*)v  + g);
        ushort4 qu = *(const ushort4*)((const unsigned short*)qp + g);
        kpT_s[(c0+0)*PS + t] = ku.x;  kpT_s[(c0+1)*PS + t] = ku.y;
        kpT_s[(c0+2)*PS + t] = ku.z;  kpT_s[(c0+3)*PS + t] = ku.w;
        vT_s [(c0+0)*PS + t] = vu.x;  vT_s [(c0+1)*PS + t] = vu.y;
        vT_s [(c0+2)*PS + t] = vu.z;  vT_s [(c0+3)*PS + t] = vu.w;
        *(ushort4*)&qp_s[t * PS + c0] = qu;
    }
    __syncthreads();

    const int wave = tid >> 6, lane = tid & 63;
    const int quad = lane >> 4, l16 = lane & 15;

    f32x4 acc[4] = {};
    #pragma unroll
    for (int kk = 0; kk < 2; ++kk) {
        bf16x8 af = *(const bf16x8*)&kpT_s[(wave*16 + l16) * PS + kk*32 + quad*8];
        #pragma unroll
        for (int ni = 0; ni < 4; ++ni) {
            bf16x8 bfr = *(const bf16x8*)&vT_s[(ni*16 + l16) * PS + kk*32 + quad*8];
            acc[ni] = __builtin_amdgcn_mfma_f32_16x16x32_bf16(af, bfr, acc[ni], 0, 0, 0);
        }
    }
    unsigned short* Sout = (unsigned short*)chunkSB + (((size_t)bh * NC + c) << 12);
    #pragma unroll
    for (int ni = 0; ni < 4; ++ni) {
        int k = ni*16 + l16;
        #pragma unroll
        for (int r = 0; r < 4; ++r) {
            int d = wave*16 + quad*4 + r;
            Sout[d * 64 + k] = f2u(acc[ni][r]);
        }
    }

    {
        int d = tid & 63, part = tid >> 6;
        float s = 0.f;
        #pragma unroll
        for (int t = part*16; t < part*16 + 16; ++t)
            s += u2f(qp_s[t * PS + d]);
        red[part][d] = s;
    }
    __syncthreads();
    if (tid < 64)
        chunkZ[((size_t)bh * NC + c) * 64 + tid] =
            red[0][tid] + red[1][tid] + red[2][tid] + red[3][tid];
}

// ---------------------------------------------------------------------------
// Pass 2: exclusive prefix over chunks (bf16 in, fp32 accumulate, bf16 out)
__global__ __launch_bounds__(256) void prefix_state(
    const bf16* __restrict__ chunkSB, bf16* __restrict__ SpB,
    float* __restrict__ chunkZ)
{
    const int bh = blockIdx.x;
    const int elem = blockIdx.y * 256 + threadIdx.x;   // 0..4095
    const unsigned short* p = (const unsigned short*)chunkSB + (((size_t)bh * NC) << 12) + elem;
    unsigned short* o = (unsigned short*)SpB + (((size_t)bh * NC) << 12) + elem;
    float run = 0.f;
    #pragma unroll
    for (int c = 0; c < NC; ++c) {
        float x = u2f(p[(size_t)c << 12]);
        o[(size_t)c << 12] = f2u(run);
        run += x;
    }
    if (blockIdx.y == 0 && threadIdx.x < 64) {
        float* pz = chunkZ + (size_t)bh * NC * 64 + threadIdx.x;
        float rz = 0.f;
        for (int c = 0; c < NC; ++c) {
            float x = pz[c * 64];
            pz[c * 64] = rz;
            rz += x;
        }
    }
}

// ---------------------------------------------------------------------------
// Pass 3 (MFMA): att = (qp@Sp + tril(qp@kp^T)@v) / (Zp + tril(1)@qp)
__global__ __launch_bounds__(256) void chunk_attn(
    const bf16* __restrict__ qp, const bf16* __restrict__ kp,
    const bf16* __restrict__ v, const bf16* __restrict__ SpB,
    const float* __restrict__ chunkZ, bf16* __restrict__ att)
{
    __shared__ __align__(16) unsigned short qp_s [64 * PS];
    __shared__ __align__(16) unsigned short kp_s [64 * PS];
    __shared__ __align__(16) unsigned short SpT_s[64 * PS];
    __shared__ __align__(16) unsigned short vT_s [64 * PS];
    __shared__ __align__(16) unsigned short qpT_s[64 * PS];
    __shared__ __align__(16) unsigned short P_s  [64 * PS];

    const int bh = blockIdx.x;
    const int c  = blockIdx.y;
    const int n  = bh >> 4, h = bh & 15;
    const int tid = threadIdx.x;
    const size_t rowbase = (size_t)n * LSEQ + (size_t)c * TCH;
    const unsigned short* Spb = (const unsigned short*)SpB + (((size_t)bh * NC + c) << 12);

    #pragma unroll
    for (int r = 0; r < 4; ++r) {
        int q = r * 256 + tid;
        int t = q >> 4, c0 = (q & 15) * 4;
        size_t g = (rowbase + t) * DM + h * HD + c0;
        ushort4 qu = *(const ushort4*)((const unsigned short*)qp + g);
        ushort4 ku = *(const ushort4*)((const unsigned short*)kp + g);
        ushort4 vu = *(const ushort4*)((const unsigned short*)v  + g);
        ushort4 su = *(const ushort4*)(Spb + q * 4);
        *(ushort4*)&qp_s[t * PS + c0] = qu;
        *(ushort4*)&kp_s[t * PS + c0] = ku;
        vT_s [(c0+0)*PS + t] = vu.x;  vT_s [(c0+1)*PS + t] = vu.y;
        vT_s [(c0+2)*PS + t] = vu.z;  vT_s [(c0+3)*PS + t] = vu.w;
        qpT_s[(c0+0)*PS + t] = qu.x;  qpT_s[(c0+1)*PS + t] = qu.y;
        qpT_s[(c0+2)*PS + t] = qu.z;  qpT_s[(c0+3)*PS + t] = qu.w;
        SpT_s[(c0+0)*PS + t] = su.x;  SpT_s[(c0+1)*PS + t] = su.y;
        SpT_s[(c0+2)*PS + t] = su.z;  SpT_s[(c0+3)*PS + t] = su.w;
    }
    __syncthreads();

    const int wave = tid >> 6, lane = tid & 63;
    const int quad = lane >> 4, l16 = lane & 15;
    const int mrow = wave * 16;

    f32x4 acc[4]  = {};
    f32x4 zacc[4] = {};
    f32x4 pacc[4] = {};

    const unsigned short ONE = 0x3F80;

    #pragma unroll
    for (int kk = 0; kk < 2; ++kk) {
        bf16x8 af = *(const bf16x8*)&qp_s[(mrow + l16) * PS + kk*32 + quad*8];
        bf16x8 tf;
        #pragma unroll
        for (int j = 0; j < 8; ++j) {
            int s = kk*32 + quad*8 + j;
            tf[j] = (short)((s <= mrow + l16) ? ONE : 0);
        }
        #pragma unroll
        for (int ni = 0; ni < 4; ++ni) {
            int boff = (ni*16 + l16) * PS + kk*32 + quad*8;
            bf16x8 b_sp = *(const bf16x8*)&SpT_s[boff];
            bf16x8 b_kp = *(const bf16x8*)&kp_s [boff];
            bf16x8 b_qt = *(const bf16x8*)&qpT_s[boff];
            acc [ni] = __builtin_amdgcn_mfma_f32_16x16x32_bf16(af, b_sp, acc [ni], 0, 0, 0);
            pacc[ni] = __builtin_amdgcn_mfma_f32_16x16x32_bf16(af, b_kp, pacc[ni], 0, 0, 0);
            zacc[ni] = __builtin_amdgcn_mfma_f32_16x16x32_bf16(tf, b_qt, zacc[ni], 0, 0, 0);
        }
    }

    #pragma unroll
    for (int ni = 0; ni < 4; ++ni) {
        int s = ni*16 + l16;
        #pragma unroll
        for (int r = 0; r < 4; ++r) {
            int t = mrow + quad*4 + r;
            float pv = (s <= t) ? pacc[ni][r] : 0.f;
            P_s[t * PS + s] = f2u(pv);
        }
    }
    __syncthreads();

    #pragma unroll
    for (int kk = 0; kk < 2; ++kk) {
        bf16x8 af = *(const bf16x8*)&P_s[(mrow + l16) * PS + kk*32 + quad*8];
        #pragma unroll
        for (int ni = 0; ni < 4; ++ni) {
            bf16x8 b_v = *(const bf16x8*)&vT_s[(ni*16 + l16) * PS + kk*32 + quad*8];
            acc[ni] = __builtin_amdgcn_mfma_f32_16x16x32_bf16(af, b_v, acc[ni], 0, 0, 0);
        }
    }

    #pragma unroll
    for (int ni = 0; ni < 4; ++ni) {
        int k = ni*16 + l16;
        float zp = chunkZ[((size_t)bh * NC + c) * 64 + k];
        #pragma unroll
        for (int r = 0; r < 4; ++r) {
            int t = mrow + quad*4 + r;
            float o = acc[ni][r] / (zp + zacc[ni][r]);
            ((unsigned short*)att)[(rowbase + t) * DM + h * HD + k] = f2u(o);
        }
    }
}

// ---------------------------------------------------------------------------
extern "C" void kernel_launch(void* const* d_in, const int* in_sizes, int n_in,
                              void* d_out, int out_size, void* d_ws, size_t ws_size,
                              hipStream_t stream)
{
    const float* queries = (const float*)d_in[0];
    const float* keys    = (const float*)d_in[1];
    const float* values  = (const float*)d_in[2];
    const float* Wq = (const float*)d_in[3];
    const float* bq = (const float*)d_in[4];
    const float* Wk = (const float*)d_in[5];
    const float* bk = (const float*)d_in[6];
    const float* Wv = (const float*)d_in[7];
    const float* bv = (const float*)d_in[8];
    const float* Wo = (const float*)d_in[9];
    const float* bo = (const float*)d_in[10];
    float* out = (float*)d_out;

    char* w = (char*)d_ws;
    const size_t E2 = (size_t)MROWS * DM * 2;   // 16,777,216
    const size_t WB = (size_t)DM * DM * 2;      //  2,097,152
    bf16* qb  = (bf16*)(w + 0 * E2);            // reused as att
    bf16* kb  = (bf16*)(w + 1 * E2);            // reused as chunkSB (bf16)
    bf16* vb  = (bf16*)(w + 2 * E2);
    bf16* Wqt = (bf16*)(w + 3 * E2 + 0 * WB);   // reused as chunkZ
    bf16* Wkt = (bf16*)(w + 3 * E2 + 1 * WB);
    bf16* Wvt = (bf16*)(w + 3 * E2 + 2 * WB);
    bf16* Wot = (bf16*)(w + 3 * E2 + 3 * WB);
    bf16* qp  = (bf16*)(w + 3 * E2 + 4 * WB);
    bf16* kp  = (bf16*)(w + 4 * E2 + 4 * WB);
    bf16* vv  = (bf16*)(w + 5 * E2 + 4 * WB);
    bf16* SpB = (bf16*)(w + 6 * E2 + 4 * WB);
    bf16*  chunkSB = kb;
    float* chunkZ  = (float*)Wqt;
    bf16*  att     = qb;

    const int n4 = (MROWS * DM) / 4;    // 2,097,152
    const int per = n4 / 256;           // 8192 blocks per tensor
    cvt3_f32_bf16<<<3 * per, 256, 0, stream>>>(queries, keys, values, qb, kb, vb, per);

    transpose_w4<<<dim3(DM / 64, DM / 64, 4), 256, 0, stream>>>(
        Wq, Wk, Wv, Wo, Wqt, Wkt, Wvt, Wot);

    // 3 projection GEMMs fused: z=0 q (elu+1), z=1 k (elu+1), z=2 v (none)
    gemm_mfma3<bf16><<<dim3(MROWS / 128, DM / 128, 3), 256, 0, stream>>>(
        qb, kb, vb, Wqt, Wkt, Wvt, bq, bk, bv, qp, kp, vv,
        0b011, MROWS, DM, DM);

    chunk_state <<<dim3(64, NC), 256, 0, stream>>>(qp, kp, vv, chunkSB, chunkZ);
    prefix_state<<<dim3(64, 16), 256, 0, stream>>>(chunkSB, SpB, chunkZ);
    chunk_attn  <<<dim3(64, NC), 256, 0, stream>>>(qp, kp, vv, SpB, chunkZ, att);

    gemm_mfma3<float><<<dim3(MROWS / 128, DM / 128, 1), 256, 0, stream>>>(
        att, att, att, Wot, Wot, Wot, bo, bo, bo, out, out, out,
        0, MROWS, DM, DM);
}

// Round 2
// 313.605 us; speedup vs baseline: 1.0106x; 1.0106x over previous
//
#include <hip/hip_runtime.h>
#include <hip/hip_bf16.h>

typedef __hip_bfloat16 bf16;

#define N_B   4
#define LSEQ  2048
#define DM    1024
#define NH    16
#define HD    64
#define MROWS (N_B * LSEQ)   // 8192
#define TCH   64
#define NC    (LSEQ / TCH)   // 32 chunks
#define PS    72             // LDS row stride (bf16 elems) for attn kernels

typedef short bf16x8 __attribute__((ext_vector_type(8)));
typedef float f32x4  __attribute__((ext_vector_type(4)));

__device__ __forceinline__ float u2f(unsigned short u){ return __uint_as_float(((unsigned)u) << 16); }
__device__ __forceinline__ unsigned short f2u(float x){
    bf16 h = __float2bfloat16(x);
    return *reinterpret_cast<unsigned short*>(&h);
}

__device__ __forceinline__ void g2l16(const void* g, void* l) {
    __builtin_amdgcn_global_load_lds(
        (const __attribute__((address_space(1))) unsigned int*)g,
        (__attribute__((address_space(3))) unsigned int*)l, 16, 0, 0);
}

// ---------------------------------------------------------------------------
// fused fp32 -> bf16 convert for 3 tensors (blockIdx.x / per selects tensor)
__global__ __launch_bounds__(256) void cvt3_f32_bf16(
    const float* __restrict__ x0, const float* __restrict__ x1, const float* __restrict__ x2,
    bf16* __restrict__ y0, bf16* __restrict__ y1, bf16* __restrict__ y2, int per)
{
    int which = blockIdx.x / per;
    const float* x = (which == 0) ? x0 : (which == 1) ? x1 : x2;
    bf16* y = (which == 0) ? y0 : (which == 1) ? y1 : y2;
    int i = (blockIdx.x - which * per) * 256 + threadIdx.x;
    float4 v = ((const float4*)x)[i];
    ushort4 o = make_ushort4(f2u(v.x), f2u(v.y), f2u(v.z), f2u(v.w));
    ((ushort4*)y)[i] = o;
}

// fused transpose for 4 weight matrices: W [K][N] fp32 -> Wt [N][K] bf16
__global__ __launch_bounds__(256) void transpose_w4(
    const float* __restrict__ W0, const float* __restrict__ W1,
    const float* __restrict__ W2, const float* __restrict__ W3,
    bf16* __restrict__ T0, bf16* __restrict__ T1,
    bf16* __restrict__ T2, bf16* __restrict__ T3)
{
    const int z = blockIdx.z;
    const float* W = (z == 0) ? W0 : (z == 1) ? W1 : (z == 2) ? W2 : W3;
    bf16* Wt = (z == 0) ? T0 : (z == 1) ? T1 : (z == 2) ? T2 : T3;

    __shared__ unsigned short t[64][65];
    const int n0 = blockIdx.x * 64;
    const int k0 = blockIdx.y * 64;
    #pragma unroll
    for (int i = 0; i < 16; ++i) {
        int e = i * 256 + threadIdx.x;
        int r = e >> 6, c = e & 63;
        t[c][r] = f2u(W[(size_t)(k0 + r) * DM + n0 + c]);
    }
    __syncthreads();
    #pragma unroll
    for (int i = 0; i < 16; ++i) {
        int e = i * 256 + threadIdx.x;
        int r = e >> 6, c = e & 63;
        ((unsigned short*)Wt)[(size_t)(n0 + r) * DM + k0 + c] = t[r][c];
    }
}

// ---------------------------------------------------------------------------
// 256x256 8-phase MFMA GEMM (HK-style schedule in plain HIP), up to 3
// problems per launch (blockIdx.z). C = act(A @ Bt^T + bias).
// BK=64 K-tiles, 4 phases/tile, one half-tile staged per phase, counted
// vmcnt(4) at tile boundaries (never 0 in steady state), setprio around MFMA.
// LDS: 2 dbuf x {A,B} x 2 halves x (128 rows x 64 cols bf16) = 128 KiB.
// Swizzle: 16B slot ^= (row&7) within each 128B row; applied on the global
// source of global_load_lds AND on ds_read (involution, rule #21).
template <typename TO>
__global__ __launch_bounds__(512, 2) void gemm_mfma3(
    const bf16* __restrict__ A0, const bf16* __restrict__ A1, const bf16* __restrict__ A2,
    const bf16* __restrict__ B0, const bf16* __restrict__ B1, const bf16* __restrict__ B2,
    const float* __restrict__ c0, const float* __restrict__ c1, const float* __restrict__ c2,
    TO* __restrict__ C0, TO* __restrict__ C1, TO* __restrict__ C2,
    int actMask, int M, int N, int K)
{
    const int z = blockIdx.z;
    const bf16* A  = (z == 0) ? A0 : (z == 1) ? A1 : A2;
    const bf16* Bt = (z == 0) ? B0 : (z == 1) ? B1 : B2;
    const float* bias = (z == 0) ? c0 : (z == 1) ? c1 : c2;
    TO* C = (z == 0) ? C0 : (z == 1) ? C1 : C2;
    const int act = (actMask >> z) & 1;

    // region(buf, ab, half) = ((buf<<2)|(ab<<1)|half) << 13   (8192 shorts)
    __shared__ __align__(16) short smem[2 * 2 * 2 * 128 * 64];   // 128 KiB

    const int tid  = threadIdx.x;
    const int m0   = blockIdx.x * 256;
    const int n0   = blockIdx.y * 256;
    const int wave = tid >> 6;
    const int lane = tid & 63;
    const int wm   = wave >> 2;          // 0..1  (M split)
    const int wn   = wave & 3;           // 0..3  (N split)
    const int quad = lane >> 4;
    const int l16  = lane & 15;
    const int xsw  = l16 & 7;            // slot-xor for swizzled frag reads

    f32x4 acc[8][4] = {};
    bf16x8 Areg[4][2], Breg[4][2];

    const int NT = K >> 6;               // 16 K-tiles of 64

    // --- staging: one half-tile (128 rows x 64 cols) = 2 x 16B per thread
    auto stageA = [&](int t, int half, int buf) {
        short* dst = smem + (((buf << 2) | 0 | half) << 13);
        #pragma unroll
        for (int i = 0; i < 2; ++i) {
            int e = i * 512 + tid;
            int r = e >> 3;
            int col = ((e & 7) ^ (r & 7)) * 8;              // pre-swizzled src
            int grow = m0 + half * 64 + (r & 63) + ((r >> 6) << 7);
            g2l16(A + (size_t)grow * K + t * 64 + col, dst + e * 8);
        }
    };
    auto stageB = [&](int t, int half, int buf) {
        short* dst = smem + (((buf << 2) | 2 | half) << 13);
        #pragma unroll
        for (int i = 0; i < 2; ++i) {
            int e = i * 512 + tid;
            int r = e >> 3;
            int col = ((e & 7) ^ (r & 7)) * 8;
            int grow = n0 + ((r >> 5) << 6) + half * 32 + (r & 31);
            g2l16(Bt + (size_t)grow * K + t * 64 + col, dst + e * 8);
        }
    };

    auto ldA = [&](const short* base, int m2, int ks) -> bf16x8 {
        int row  = wm * 64 + m2 * 16 + l16;
        int slot = (ks * 4 + quad) ^ xsw;
        return *(const bf16x8*)(base + row * 64 + slot * 8);
    };
    auto ldB = [&](const short* base, int n2, int ks) -> bf16x8 {
        int row  = wn * 32 + n2 * 16 + l16;
        int slot = (ks * 4 + quad) ^ xsw;
        return *(const bf16x8*)(base + row * 64 + slot * 8);
    };

    // --- prologue: T0 fully, T1.{A0,B0}; then wait so T0 is landed
    stageA(0, 0, 0); stageB(0, 0, 0); stageB(0, 1, 0); stageA(0, 1, 0);
    stageA(1, 0, 1); stageB(1, 0, 1);
    asm volatile("s_waitcnt vmcnt(4)" ::: "memory");
    asm volatile("s_barrier" ::: "memory");

    for (int T = 0; T < NT; ++T) {
        const int bT = T & 1;
        const short* Ab0 = smem + (((bT << 2) | 0 | 0) << 13);
        const short* Ab1 = smem + (((bT << 2) | 0 | 1) << 13);
        const short* Bb0 = smem + (((bT << 2) | 2 | 0) << 13);
        const short* Bb1 = smem + (((bT << 2) | 2 | 1) << 13);

        // ---- phase 1: read A-half0 + B-half0; stage (T+1).B1; MFMA q(0,0)
        #pragma unroll
        for (int m2 = 0; m2 < 4; ++m2) {
            Areg[m2][0] = ldA(Ab0, m2, 0);
            Areg[m2][1] = ldA(Ab0, m2, 1);
        }
        #pragma unroll
        for (int n2 = 0; n2 < 2; ++n2) {
            Breg[n2][0] = ldB(Bb0, n2, 0);
            Breg[n2][1] = ldB(Bb0, n2, 1);
        }
        if (T + 1 < NT) stageB(T + 1, 1, (T + 1) & 1);
        asm volatile("s_barrier" ::: "memory");
        __builtin_amdgcn_s_setprio(1);
        #pragma unroll
        for (int m2 = 0; m2 < 4; ++m2)
            #pragma unroll
            for (int n2 = 0; n2 < 2; ++n2) {
                acc[m2][n2] = __builtin_amdgcn_mfma_f32_16x16x32_bf16(
                    Areg[m2][0], Breg[n2][0], acc[m2][n2], 0, 0, 0);
                acc[m2][n2] = __builtin_amdgcn_mfma_f32_16x16x32_bf16(
                    Areg[m2][1], Breg[n2][1], acc[m2][n2], 0, 0, 0);
            }
        __builtin_amdgcn_s_setprio(0);
        asm volatile("s_barrier" ::: "memory");

        // ---- phase 2: read B-half1; stage (T+1).A1; MFMA q(0,1)
        #pragma unroll
        for (int n2 = 0; n2 < 2; ++n2) {
            Breg[2 + n2][0] = ldB(Bb1, n2, 0);
            Breg[2 + n2][1] = ldB(Bb1, n2, 1);
        }
        if (T + 1 < NT) stageA(T + 1, 1, (T + 1) & 1);
        asm volatile("s_barrier" ::: "memory");
        __builtin_amdgcn_s_setprio(1);
        #pragma unroll
        for (int m2 = 0; m2 < 4; ++m2)
            #pragma unroll
            for (int n2 = 0; n2 < 2; ++n2) {
                acc[m2][2 + n2] = __builtin_amdgcn_mfma_f32_16x16x32_bf16(
                    Areg[m2][0], Breg[2 + n2][0], acc[m2][2 + n2], 0, 0, 0);
                acc[m2][2 + n2] = __builtin_amdgcn_mfma_f32_16x16x32_bf16(
                    Areg[m2][1], Breg[2 + n2][1], acc[m2][2 + n2], 0, 0, 0);
            }
        __builtin_amdgcn_s_setprio(0);
        asm volatile("s_barrier" ::: "memory");

        // ---- phase 3: read A-half1; stage (T+2).A0 (same buf, A0 done @p1);
        //      MFMA q(1,0)
        #pragma unroll
        for (int m2 = 0; m2 < 4; ++m2) {
            Areg[m2][0] = ldA(Ab1, m2, 0);
            Areg[m2][1] = ldA(Ab1, m2, 1);
        }
        if (T + 2 < NT) stageA(T + 2, 0, bT);
        asm volatile("s_barrier" ::: "memory");
        __builtin_amdgcn_s_setprio(1);
        #pragma unroll
        for (int m2 = 0; m2 < 4; ++m2)
            #pragma unroll
            for (int n2 = 0; n2 < 2; ++n2) {
                acc[4 + m2][n2] = __builtin_amdgcn_mfma_f32_16x16x32_bf16(
                    Areg[m2][0], Breg[n2][0], acc[4 + m2][n2], 0, 0, 0);
                acc[4 + m2][n2] = __builtin_amdgcn_mfma_f32_16x16x32_bf16(
                    Areg[m2][1], Breg[n2][1], acc[4 + m2][n2], 0, 0, 0);
            }
        __builtin_amdgcn_s_setprio(0);
        asm volatile("s_barrier" ::: "memory");

        // ---- phase 4: no reads; stage (T+2).B0 (B0 done @p1); MFMA q(1,1);
        //      boundary: counted vmcnt BEFORE the publishing barrier
        if (T + 2 < NT) stageB(T + 2, 0, bT);
        asm volatile("s_barrier" ::: "memory");
        __builtin_amdgcn_s_setprio(1);
        #pragma unroll
        for (int m2 = 0; m2 < 4; ++m2)
            #pragma unroll
            for (int n2 = 0; n2 < 2; ++n2) {
                acc[4 + m2][2 + n2] = __builtin_amdgcn_mfma_f32_16x16x32_bf16(
                    Areg[m2][0], Breg[2 + n2][0], acc[4 + m2][2 + n2], 0, 0, 0);
                acc[4 + m2][2 + n2] = __builtin_amdgcn_mfma_f32_16x16x32_bf16(
                    Areg[m2][1], Breg[2 + n2][1], acc[4 + m2][2 + n2], 0, 0, 0);
            }
        __builtin_amdgcn_s_setprio(0);
        if (T < NT - 2)
            asm volatile("s_waitcnt vmcnt(4)" ::: "memory");
        else
            asm volatile("s_waitcnt vmcnt(0)" ::: "memory");
        asm volatile("s_barrier" ::: "memory");
    }

    // ---- epilogue
    #pragma unroll
    for (int ni = 0; ni < 4; ++ni) {
        int col = n0 + wn * 64 + ni * 16 + l16;
        float bv = bias[col];
        #pragma unroll
        for (int mi = 0; mi < 8; ++mi) {
            #pragma unroll
            for (int r = 0; r < 4; ++r) {
                int row = m0 + wm * 128 + mi * 16 + quad * 4 + r;
                float x = acc[mi][ni][r] + bv;
                if (act) x = (x > 0.f) ? (x + 1.f) : __expf(x);
                if constexpr (sizeof(TO) == 2)
                    ((bf16*)C)[(size_t)row * N + col] = __float2bfloat16(x);
                else
                    ((float*)C)[(size_t)row * N + col] = x;
            }
        }
    }
}

// ---------------------------------------------------------------------------
// Pass 1 (MFMA): chunkSB[d][k] = sum_t kp[t][d]*v[t][k] (bf16); chunkZ fp32
__global__ __launch_bounds__(256) void chunk_state(
    const bf16* __restrict__ qp, const bf16* __restrict__ kp,
    const bf16* __restrict__ v,
    bf16* __restrict__ chunkSB, float* __restrict__ chunkZ)
{
    __shared__ __align__(16) unsigned short kpT_s[64 * PS];
    __shared__ __align__(16) unsigned short vT_s [64 * PS];
    __shared__ __align__(16) unsigned short qp_s [64 * PS];
    __shared__ float red[4][64];

    const int bh = blockIdx.x;
    const int c  = blockIdx.y;
    const int n  = bh >> 4, h = bh & 15;
    const int tid = threadIdx.x;
    const size_t rowbase = (size_t)n * LSEQ + (size_t)c * TCH;

    #pragma unroll
    for (int r = 0; r < 4; ++r) {
        int q = r * 256 + tid;
        int t = q >> 4, c0 = (q & 15) * 4;
        size_t g = (rowbase + t) * DM + h * HD + c0;
        ushort4 ku = *(const ushort4*)((const unsigned short*)kp + g);
        ushort4 vu = *(const ushort4*)((const unsigned short*)v  + g);
        ushort4 qu = *(const ushort4*)((const unsigned short*)qp + g);
        kpT_s[(c0+0)*PS + t] = ku.x;  kpT_s[(c0+1)*PS + t] = ku.y;
        kpT_s[(c0+2)*PS + t] = ku.z;  kpT_s[(c0+3)*PS + t] = ku.w;
        vT_s [(c0+0)*PS + t] = vu.x;  vT_s [(c0+1)*PS + t] = vu.y;
        vT_s [(c0+2)*PS + t] = vu.z;  vT_s [(c0+3)*PS + t] = vu.w;
        *(ushort4*)&qp_s[t * PS + c0] = qu;
    }
    __syncthreads();

    const int wave = tid >> 6, lane = tid & 63;
    const int quad = lane >> 4, l16 = lane & 15;

    f32x4 acc[4] = {};
    #pragma unroll
    for (int kk = 0; kk < 2; ++kk) {
        bf16x8 af = *(const bf16x8*)&kpT_s[(wave*16 + l16) * PS + kk*32 + quad*8];
        #pragma unroll
        for (int ni = 0; ni < 4; ++ni) {
            bf16x8 bfr = *(const bf16x8*)&vT_s[(ni*16 + l16) * PS + kk*32 + quad*8];
            acc[ni] = __builtin_amdgcn_mfma_f32_16x16x32_bf16(af, bfr, acc[ni], 0, 0, 0);
        }
    }
    unsigned short* Sout = (unsigned short*)chunkSB + (((size_t)bh * NC + c) << 12);
    #pragma unroll
    for (int ni = 0; ni < 4; ++ni) {
        int k = ni*16 + l16;
        #pragma unroll
        for (int r = 0; r < 4; ++r) {
            int d = wave*16 + quad*4 + r;
            Sout[d * 64 + k] = f2u(acc[ni][r]);
        }
    }

    {
        int d = tid & 63, part = tid >> 6;
        float s = 0.f;
        #pragma unroll
        for (int t = part*16; t < part*16 + 16; ++t)
            s += u2f(qp_s[t * PS + d]);
        red[part][d] = s;
    }
    __syncthreads();
    if (tid < 64)
        chunkZ[((size_t)bh * NC + c) * 64 + tid] =
            red[0][tid] + red[1][tid] + red[2][tid] + red[3][tid];
}

// ---------------------------------------------------------------------------
// Pass 2: exclusive prefix over chunks (bf16 in, fp32 accumulate, bf16 out)
__global__ __launch_bounds__(256) void prefix_state(
    const bf16* __restrict__ chunkSB, bf16* __restrict__ SpB,
    float* __restrict__ chunkZ)
{
    const int bh = blockIdx.x;
    const int elem = blockIdx.y * 256 + threadIdx.x;   // 0..4095
    const unsigned short* p = (const unsigned short*)chunkSB + (((size_t)bh * NC) << 12) + elem;
    unsigned short* o = (unsigned short*)SpB + (((size_t)bh * NC) << 12) + elem;
    float run = 0.f;
    #pragma unroll
    for (int c = 0; c < NC; ++c) {
        float x = u2f(p[(size_t)c << 12]);
        o[(size_t)c << 12] = f2u(run);
        run += x;
    }
    if (blockIdx.y == 0 && threadIdx.x < 64) {
        float* pz = chunkZ + (size_t)bh * NC * 64 + threadIdx.x;
        float rz = 0.f;
        for (int c = 0; c < NC; ++c) {
            float x = pz[c * 64];
            pz[c * 64] = rz;
            rz += x;
        }
    }
}

// ---------------------------------------------------------------------------
// Pass 3 (MFMA): att = (qp@Sp + tril(qp@kp^T)@v) / (Zp + tril(1)@qp)
__global__ __launch_bounds__(256) void chunk_attn(
    const bf16* __restrict__ qp, const bf16* __restrict__ kp,
    const bf16* __restrict__ v, const bf16* __restrict__ SpB,
    const float* __restrict__ chunkZ, bf16* __restrict__ att)
{
    __shared__ __align__(16) unsigned short qp_s [64 * PS];
    __shared__ __align__(16) unsigned short kp_s [64 * PS];
    __shared__ __align__(16) unsigned short SpT_s[64 * PS];
    __shared__ __align__(16) unsigned short vT_s [64 * PS];
    __shared__ __align__(16) unsigned short qpT_s[64 * PS];
    __shared__ __align__(16) unsigned short P_s  [64 * PS];

    const int bh = blockIdx.x;
    const int c  = blockIdx.y;
    const int n  = bh >> 4, h = bh & 15;
    const int tid = threadIdx.x;
    const size_t rowbase = (size_t)n * LSEQ + (size_t)c * TCH;
    const unsigned short* Spb = (const unsigned short*)SpB + (((size_t)bh * NC + c) << 12);

    #pragma unroll
    for (int r = 0; r < 4; ++r) {
        int q = r * 256 + tid;
        int t = q >> 4, c0 = (q & 15) * 4;
        size_t g = (rowbase + t) * DM + h * HD + c0;
        ushort4 qu = *(const ushort4*)((const unsigned short*)qp + g);
        ushort4 ku = *(const ushort4*)((const unsigned short*)kp + g);
        ushort4 vu = *(const ushort4*)((const unsigned short*)v  + g);
        ushort4 su = *(const ushort4*)(Spb + q * 4);
        *(ushort4*)&qp_s[t * PS + c0] = qu;
        *(ushort4*)&kp_s[t * PS + c0] = ku;
        vT_s [(c0+0)*PS + t] = vu.x;  vT_s [(c0+1)*PS + t] = vu.y;
        vT_s [(c0+2)*PS + t] = vu.z;  vT_s [(c0+3)*PS + t] = vu.w;
        qpT_s[(c0+0)*PS + t] = qu.x;  qpT_s[(c0+1)*PS + t] = qu.y;
        qpT_s[(c0+2)*PS + t] = qu.z;  qpT_s[(c0+3)*PS + t] = qu.w;
        SpT_s[(c0+0)*PS + t] = su.x;  SpT_s[(c0+1)*PS + t] = su.y;
        SpT_s[(c0+2)*PS + t] = su.z;  SpT_s[(c0+3)*PS + t] = su.w;
    }
    __syncthreads();

    const int wave = tid >> 6, lane = tid & 63;
    const int quad = lane >> 4, l16 = lane & 15;
    const int mrow = wave * 16;

    f32x4 acc[4]  = {};
    f32x4 zacc[4] = {};
    f32x4 pacc[4] = {};

    const unsigned short ONE = 0x3F80;

    #pragma unroll
    for (int kk = 0; kk < 2; ++kk) {
        bf16x8 af = *(const bf16x8*)&qp_s[(mrow + l16) * PS + kk*32 + quad*8];
        bf16x8 tf;
        #pragma unroll
        for (int j = 0; j < 8; ++j) {
            int s = kk*32 + quad*8 + j;
            tf[j] = (short)((s <= mrow + l16) ? ONE : 0);
        }
        #pragma unroll
        for (int ni = 0; ni < 4; ++ni) {
            int boff = (ni*16 + l16) * PS + kk*32 + quad*8;
            bf16x8 b_sp = *(const bf16x8*)&SpT_s[boff];
            bf16x8 b_kp = *(const bf16x8*)&kp_s [boff];
            bf16x8 b_qt = *(const bf16x8*)&qpT_s[boff];
            acc [ni] = __builtin_amdgcn_mfma_f32_16x16x32_bf16(af, b_sp, acc [ni], 0, 0, 0);
            pacc[ni] = __builtin_amdgcn_mfma_f32_16x16x32_bf16(af, b_kp, pacc[ni], 0, 0, 0);
            zacc[ni] = __builtin_amdgcn_mfma_f32_16x16x32_bf16(tf, b_qt, zacc[ni], 0, 0, 0);
        }
    }

    #pragma unroll
    for (int ni = 0; ni < 4; ++ni) {
        int s = ni*16 + l16;
        #pragma unroll
        for (int r = 0; r < 4; ++r) {
            int t = mrow + quad*4 + r;
            float pv = (s <= t) ? pacc[ni][r] : 0.f;
            P_s[t * PS + s] = f2u(pv);
        }
    }
    __syncthreads();

    #pragma unroll
    for (int kk = 0; kk < 2; ++kk) {
        bf16x8 af = *(const bf16x8*)&P_s[(mrow + l16) * PS + kk*32 + quad*8];
        #pragma unroll
        for (int ni = 0; ni < 4; ++ni) {
            bf16x8 b_v = *(const bf16x8*)&vT_s[(ni*16 + l16) * PS + kk*32 + quad*8];
            acc[ni] = __builtin_amdgcn_mfma_f32_16x16x32_bf16(af, b_v, acc[ni], 0, 0, 0);
        }
    }

    #pragma unroll
    for (int ni = 0; ni < 4; ++ni) {
        int k = ni*16 + l16;
        float zp = chunkZ[((size_t)bh * NC + c) * 64 + k];
        #pragma unroll
        for (int r = 0; r < 4; ++r) {
            int t = mrow + quad*4 + r;
            float o = acc[ni][r] / (zp + zacc[ni][r]);
            ((unsigned short*)att)[(rowbase + t) * DM + h * HD + k] = f2u(o);
        }
    }
}

// ---------------------------------------------------------------------------
extern "C" void kernel_launch(void* const* d_in, const int* in_sizes, int n_in,
                              void* d_out, int out_size, void* d_ws, size_t ws_size,
                              hipStream_t stream)
{
    const float* queries = (const float*)d_in[0];
    const float* keys    = (const float*)d_in[1];
    const float* values  = (const float*)d_in[2];
    const float* Wq = (const float*)d_in[3];
    const float* bq = (const float*)d_in[4];
    const float* Wk = (const float*)d_in[5];
    const float* bk = (const float*)d_in[6];
    const float* Wv = (const float*)d_in[7];
    const float* bv = (const float*)d_in[8];
    const float* Wo = (const float*)d_in[9];
    const float* bo = (const float*)d_in[10];
    float* out = (float*)d_out;

    char* w = (char*)d_ws;
    const size_t E2 = (size_t)MROWS * DM * 2;   // 16,777,216
    const size_t WB = (size_t)DM * DM * 2;      //  2,097,152
    bf16* qb  = (bf16*)(w + 0 * E2);            // reused as att
    bf16* kb  = (bf16*)(w + 1 * E2);            // reused as chunkSB (bf16)
    bf16* vb  = (bf16*)(w + 2 * E2);
    bf16* Wqt = (bf16*)(w + 3 * E2 + 0 * WB);   // reused as chunkZ
    bf16* Wkt = (bf16*)(w + 3 * E2 + 1 * WB);
    bf16* Wvt = (bf16*)(w + 3 * E2 + 2 * WB);
    bf16* Wot = (bf16*)(w + 3 * E2 + 3 * WB);
    bf16* qp  = (bf16*)(w + 3 * E2 + 4 * WB);
    bf16* kp  = (bf16*)(w + 4 * E2 + 4 * WB);
    bf16* vv  = (bf16*)(w + 5 * E2 + 4 * WB);
    bf16* SpB = (bf16*)(w + 6 * E2 + 4 * WB);
    bf16*  chunkSB = kb;
    float* chunkZ  = (float*)Wqt;
    bf16*  att     = qb;

    const int n4 = (MROWS * DM) / 4;    // 2,097,152
    const int per = n4 / 256;           // 8192 blocks per tensor
    cvt3_f32_bf16<<<3 * per, 256, 0, stream>>>(queries, keys, values, qb, kb, vb, per);

    transpose_w4<<<dim3(DM / 64, DM / 64, 4), 256, 0, stream>>>(
        Wq, Wk, Wv, Wo, Wqt, Wkt, Wvt, Wot);

    // 3 projection GEMMs fused: z=0 q (elu+1), z=1 k (elu+1), z=2 v (none)
    gemm_mfma3<bf16><<<dim3(MROWS / 256, DM / 256, 3), 512, 0, stream>>>(
        qb, kb, vb, Wqt, Wkt, Wvt, bq, bk, bv, qp, kp, vv,
        0b011, MROWS, DM, DM);

    chunk_state <<<dim3(64, NC), 256, 0, stream>>>(qp, kp, vv, chunkSB, chunkZ);
    prefix_state<<<dim3(64, 16), 256, 0, stream>>>(chunkSB, SpB, chunkZ);
    chunk_attn  <<<dim3(64, NC), 256, 0, stream>>>(qp, kp, vv, SpB, chunkZ, att);

    gemm_mfma3<float><<<dim3(MROWS / 256, DM / 256, 1), 512, 0, stream>>>(
        att, att, att, Wot, Wot, Wot, bo, bo, bo, out, out, out,
        0, MROWS, DM, DM);
}

// Round 3
// 300.931 us; speedup vs baseline: 1.0531x; 1.0421x over previous
//
#include <hip/hip_runtime.h>
#include <hip/hip_bf16.h>

typedef __hip_bfloat16 bf16;

#define N_B   4
#define LSEQ  2048
#define DM    1024
#define NH    16
#define HD    64
#define MROWS (N_B * LSEQ)   // 8192
#define TCH   64
#define NC    (LSEQ / TCH)   // 32 chunks
#define PS    72             // LDS row stride (bf16 elems) for attn kernels

typedef short bf16x8 __attribute__((ext_vector_type(8)));
typedef float f32x4  __attribute__((ext_vector_type(4)));

__device__ __forceinline__ float u2f(unsigned short u){ return __uint_as_float(((unsigned)u) << 16); }
__device__ __forceinline__ unsigned short f2u(float x){
    bf16 h = __float2bfloat16(x);
    return *reinterpret_cast<unsigned short*>(&h);
}

__device__ __forceinline__ void g2l16(const void* g, void* l) {
    __builtin_amdgcn_global_load_lds(
        (const __attribute__((address_space(1))) unsigned int*)g,
        (__attribute__((address_space(3))) unsigned int*)l, 16, 0, 0);
}

// 4x4 bf16 transpose in-register: v[j] = row j (4 bf16 in uint2), o[i] = col i.
__device__ __forceinline__ void tr4x4(const uint2 v[4], uint2 o[4]) {
    o[0].x = __builtin_amdgcn_perm(v[1].x, v[0].x, 0x05040100u);
    o[0].y = __builtin_amdgcn_perm(v[3].x, v[2].x, 0x05040100u);
    o[1].x = __builtin_amdgcn_perm(v[1].x, v[0].x, 0x07060302u);
    o[1].y = __builtin_amdgcn_perm(v[3].x, v[2].x, 0x07060302u);
    o[2].x = __builtin_amdgcn_perm(v[1].y, v[0].y, 0x05040100u);
    o[2].y = __builtin_amdgcn_perm(v[3].y, v[2].y, 0x05040100u);
    o[3].x = __builtin_amdgcn_perm(v[1].y, v[0].y, 0x07060302u);
    o[3].y = __builtin_amdgcn_perm(v[3].y, v[2].y, 0x07060302u);
}

// ---------------------------------------------------------------------------
// fused fp32 -> bf16 convert for 3 tensors (blockIdx.x / per selects tensor)
__global__ __launch_bounds__(256) void cvt3_f32_bf16(
    const float* __restrict__ x0, const float* __restrict__ x1, const float* __restrict__ x2,
    bf16* __restrict__ y0, bf16* __restrict__ y1, bf16* __restrict__ y2, int per)
{
    int which = blockIdx.x / per;
    const float* x = (which == 0) ? x0 : (which == 1) ? x1 : x2;
    bf16* y = (which == 0) ? y0 : (which == 1) ? y1 : y2;
    int i = (blockIdx.x - which * per) * 256 + threadIdx.x;
    float4 v = ((const float4*)x)[i];
    ushort4 o = make_ushort4(f2u(v.x), f2u(v.y), f2u(v.z), f2u(v.w));
    ((ushort4*)y)[i] = o;
}

// fused transpose for 4 weight matrices: W [K][N] fp32 -> Wt [N][K] bf16
__global__ __launch_bounds__(256) void transpose_w4(
    const float* __restrict__ W0, const float* __restrict__ W1,
    const float* __restrict__ W2, const float* __restrict__ W3,
    bf16* __restrict__ T0, bf16* __restrict__ T1,
    bf16* __restrict__ T2, bf16* __restrict__ T3)
{
    const int z = blockIdx.z;
    const float* W = (z == 0) ? W0 : (z == 1) ? W1 : (z == 2) ? W2 : W3;
    bf16* Wt = (z == 0) ? T0 : (z == 1) ? T1 : (z == 2) ? T2 : T3;

    __shared__ unsigned short t[64][65];
    const int n0 = blockIdx.x * 64;
    const int k0 = blockIdx.y * 64;
    #pragma unroll
    for (int i = 0; i < 16; ++i) {
        int e = i * 256 + threadIdx.x;
        int r = e >> 6, c = e & 63;
        t[c][r] = f2u(W[(size_t)(k0 + r) * DM + n0 + c]);
    }
    __syncthreads();
    #pragma unroll
    for (int i = 0; i < 16; ++i) {
        int e = i * 256 + threadIdx.x;
        int r = e >> 6, c = e & 63;
        ((unsigned short*)Wt)[(size_t)(n0 + r) * DM + k0 + c] = t[r][c];
    }
}

// ---------------------------------------------------------------------------
// BMx256 4-phase MFMA GEMM (HK-style schedule), up to 3 problems per launch.
// MF = M-fragments per wave (8 -> BM=256, 4 -> BM=128). BK=64 K-tiles, one
// half-tile staged per phase, counted vmcnt at tile boundaries (never 0 in
// steady state), setprio around MFMA clusters. XOR-swizzled LDS (involution
// applied on global source AND ds_read slot).
template <typename TO, int MF>
__global__ __launch_bounds__(512, 2) void gemm_mfma3(
    const bf16* __restrict__ A0, const bf16* __restrict__ A1, const bf16* __restrict__ A2,
    const bf16* __restrict__ B0, const bf16* __restrict__ B1, const bf16* __restrict__ B2,
    const float* __restrict__ c0, const float* __restrict__ c1, const float* __restrict__ c2,
    TO* __restrict__ C0, TO* __restrict__ C1, TO* __restrict__ C2,
    int actMask, int M, int N, int K)
{
    constexpr int BM  = MF * 32;        // 256 or 128
    constexpr int MH  = MF / 2;         // m-frags per phase quadrant
    constexpr int ASZ = MF * 16 * 64;   // shorts per A half-region
    constexpr int BSZ = 128 * 64;       // shorts per B half-region
    constexpr int LA  = MF / 4;         // g2l16 per thread per A half (2 or 1)
    constexpr int RSZ = 2 * ASZ + 2 * BSZ;

    const int z = blockIdx.z;
    const bf16* A  = (z == 0) ? A0 : (z == 1) ? A1 : A2;
    const bf16* Bt = (z == 0) ? B0 : (z == 1) ? B1 : B2;
    const float* bias = (z == 0) ? c0 : (z == 1) ? c1 : c2;
    TO* C = (z == 0) ? C0 : (z == 1) ? C1 : C2;
    const int act = (actMask >> z) & 1;

    __shared__ __align__(16) short smem[2 * RSZ];

    const int tid  = threadIdx.x;
    const int m0   = blockIdx.x * BM;
    const int n0   = blockIdx.y * 256;
    const int wave = tid >> 6;
    const int lane = tid & 63;
    const int wm   = wave >> 2;          // 0..1  (M split)
    const int wn   = wave & 3;           // 0..3  (N split)
    const int quad = lane >> 4;
    const int l16  = lane & 15;
    const int xsw  = l16 & 7;            // slot-xor for swizzled frag reads

    f32x4 acc[MF][4] = {};
    bf16x8 Areg[MH][2], Breg[4][2];

    const int NT = K >> 6;               // 16 K-tiles of 64

    auto regA = [&](int buf, int h) -> short* { return smem + buf * RSZ + h * ASZ; };
    auto regB = [&](int buf, int h) -> short* { return smem + buf * RSZ + 2 * ASZ + h * BSZ; };

    // stage one A half-tile (MF*16 rows x 64 cols)
    auto stageA = [&](int t, int half, int buf) {
        short* dst = regA(buf, half);
        #pragma unroll
        for (int i = 0; i < LA; ++i) {
            int e = i * 512 + tid;
            int r = e >> 3;
            int col = ((e & 7) ^ (r & 7)) * 8;              // pre-swizzled src
            int grow = m0 + half * (MH * 16) + (r >> (MH == 4 ? 6 : 5)) * (MF * 16)
                       + (r & (MH * 16 - 1));
            g2l16(A + (size_t)grow * K + t * 64 + col, dst + e * 8);
        }
    };
    // stage one B half-tile (128 rows x 64 cols)
    auto stageB = [&](int t, int half, int buf) {
        short* dst = regB(buf, half);
        #pragma unroll
        for (int i = 0; i < 2; ++i) {
            int e = i * 512 + tid;
            int r = e >> 3;
            int col = ((e & 7) ^ (r & 7)) * 8;
            int grow = n0 + ((r >> 5) << 6) + half * 32 + (r & 31);
            g2l16(Bt + (size_t)grow * K + t * 64 + col, dst + e * 8);
        }
    };

    auto ldA = [&](const short* base, int m2, int ks) -> bf16x8 {
        int row  = wm * (MH * 16) + m2 * 16 + l16;
        int slot = (ks * 4 + quad) ^ xsw;
        return *(const bf16x8*)(base + row * 64 + slot * 8);
    };
    auto ldB = [&](const short* base, int n2, int ks) -> bf16x8 {
        int row  = wn * 32 + n2 * 16 + l16;
        int slot = (ks * 4 + quad) ^ xsw;
        return *(const bf16x8*)(base + row * 64 + slot * 8);
    };

    // --- prologue: T0 fully, T1.{A0,B0}; wait so T0 is landed
    stageA(0, 0, 0); stageB(0, 0, 0); stageB(0, 1, 0); stageA(0, 1, 0);
    stageA(1, 0, 1); stageB(1, 0, 1);
    if constexpr (MF == 8) asm volatile("s_waitcnt vmcnt(4)" ::: "memory");
    else                   asm volatile("s_waitcnt vmcnt(3)" ::: "memory");
    asm volatile("s_barrier" ::: "memory");

    for (int T = 0; T < NT; ++T) {
        const int bT = T & 1;
        const short* Ab0 = regA(bT, 0);
        const short* Ab1 = regA(bT, 1);
        const short* Bb0 = regB(bT, 0);
        const short* Bb1 = regB(bT, 1);

        // ---- phase 1: read A-h0 + B-h0; stage (T+1).B1; MFMA q(0,0)
        #pragma unroll
        for (int m2 = 0; m2 < MH; ++m2) {
            Areg[m2][0] = ldA(Ab0, m2, 0);
            Areg[m2][1] = ldA(Ab0, m2, 1);
        }
        #pragma unroll
        for (int n2 = 0; n2 < 2; ++n2) {
            Breg[n2][0] = ldB(Bb0, n2, 0);
            Breg[n2][1] = ldB(Bb0, n2, 1);
        }
        if (T + 1 < NT) stageB(T + 1, 1, (T + 1) & 1);
        asm volatile("s_barrier" ::: "memory");
        __builtin_amdgcn_s_setprio(1);
        #pragma unroll
        for (int m2 = 0; m2 < MH; ++m2)
            #pragma unroll
            for (int n2 = 0; n2 < 2; ++n2) {
                acc[m2][n2] = __builtin_amdgcn_mfma_f32_16x16x32_bf16(
                    Areg[m2][0], Breg[n2][0], acc[m2][n2], 0, 0, 0);
                acc[m2][n2] = __builtin_amdgcn_mfma_f32_16x16x32_bf16(
                    Areg[m2][1], Breg[n2][1], acc[m2][n2], 0, 0, 0);
            }
        __builtin_amdgcn_s_setprio(0);
        asm volatile("s_barrier" ::: "memory");

        // ---- phase 2: read B-h1; stage (T+1).A1; MFMA q(0,1)
        #pragma unroll
        for (int n2 = 0; n2 < 2; ++n2) {
            Breg[2 + n2][0] = ldB(Bb1, n2, 0);
            Breg[2 + n2][1] = ldB(Bb1, n2, 1);
        }
        if (T + 1 < NT) stageA(T + 1, 1, (T + 1) & 1);
        asm volatile("s_barrier" ::: "memory");
        __builtin_amdgcn_s_setprio(1);
        #pragma unroll
        for (int m2 = 0; m2 < MH; ++m2)
            #pragma unroll
            for (int n2 = 0; n2 < 2; ++n2) {
                acc[m2][2 + n2] = __builtin_amdgcn_mfma_f32_16x16x32_bf16(
                    Areg[m2][0], Breg[2 + n2][0], acc[m2][2 + n2], 0, 0, 0);
                acc[m2][2 + n2] = __builtin_amdgcn_mfma_f32_16x16x32_bf16(
                    Areg[m2][1], Breg[2 + n2][1], acc[m2][2 + n2], 0, 0, 0);
            }
        __builtin_amdgcn_s_setprio(0);
        asm volatile("s_barrier" ::: "memory");

        // ---- phase 3: read A-h1; stage (T+2).A0; MFMA q(1,0)
        #pragma unroll
        for (int m2 = 0; m2 < MH; ++m2) {
            Areg[m2][0] = ldA(Ab1, m2, 0);
            Areg[m2][1] = ldA(Ab1, m2, 1);
        }
        if (T + 2 < NT) stageA(T + 2, 0, bT);
        asm volatile("s_barrier" ::: "memory");
        __builtin_amdgcn_s_setprio(1);
        #pragma unroll
        for (int m2 = 0; m2 < MH; ++m2)
            #pragma unroll
            for (int n2 = 0; n2 < 2; ++n2) {
                acc[MH + m2][n2] = __builtin_amdgcn_mfma_f32_16x16x32_bf16(
                    Areg[m2][0], Breg[n2][0], acc[MH + m2][n2], 0, 0, 0);
                acc[MH + m2][n2] = __builtin_amdgcn_mfma_f32_16x16x32_bf16(
                    Areg[m2][1], Breg[n2][1], acc[MH + m2][n2], 0, 0, 0);
            }
        __builtin_amdgcn_s_setprio(0);
        asm volatile("s_barrier" ::: "memory");

        // ---- phase 4: stage (T+2).B0; MFMA q(1,1); boundary counted vmcnt
        if (T + 2 < NT) stageB(T + 2, 0, bT);
        asm volatile("s_barrier" ::: "memory");
        __builtin_amdgcn_s_setprio(1);
        #pragma unroll
        for (int m2 = 0; m2 < MH; ++m2)
            #pragma unroll
            for (int n2 = 0; n2 < 2; ++n2) {
                acc[MH + m2][2 + n2] = __builtin_amdgcn_mfma_f32_16x16x32_bf16(
                    Areg[m2][0], Breg[2 + n2][0], acc[MH + m2][2 + n2], 0, 0, 0);
                acc[MH + m2][2 + n2] = __builtin_amdgcn_mfma_f32_16x16x32_bf16(
                    Areg[m2][1], Breg[2 + n2][1], acc[MH + m2][2 + n2], 0, 0, 0);
            }
        __builtin_amdgcn_s_setprio(0);
        if (T < NT - 2) {
            if constexpr (MF == 8) asm volatile("s_waitcnt vmcnt(4)" ::: "memory");
            else                   asm volatile("s_waitcnt vmcnt(3)" ::: "memory");
        } else {
            asm volatile("s_waitcnt vmcnt(0)" ::: "memory");
        }
        asm volatile("s_barrier" ::: "memory");
    }

    // ---- epilogue
    #pragma unroll
    for (int ni = 0; ni < 4; ++ni) {
        int col = n0 + wn * 64 + ni * 16 + l16;
        float bv = bias[col];
        #pragma unroll
        for (int mi = 0; mi < MF; ++mi) {
            #pragma unroll
            for (int r = 0; r < 4; ++r) {
                int row = m0 + wm * (MF * 16) + mi * 16 + quad * 4 + r;
                float x = acc[mi][ni][r] + bv;
                if (act) x = (x > 0.f) ? (x + 1.f) : __expf(x);
                if constexpr (sizeof(TO) == 2)
                    ((bf16*)C)[(size_t)row * N + col] = __float2bfloat16(x);
                else
                    ((float*)C)[(size_t)row * N + col] = x;
            }
        }
    }
}

// ---------------------------------------------------------------------------
// Pass 1 (MFMA): chunkSB[d][k] = sum_t kp[t][d]*v[t][k] (bf16); chunkZ fp32
__global__ __launch_bounds__(256) void chunk_state(
    const bf16* __restrict__ qp, const bf16* __restrict__ kp,
    const bf16* __restrict__ v,
    bf16* __restrict__ chunkSB, float* __restrict__ chunkZ)
{
    __shared__ __align__(16) unsigned short kpT_s[64 * PS];
    __shared__ __align__(16) unsigned short vT_s [64 * PS];
    __shared__ __align__(16) unsigned short qp_s [64 * PS];
    __shared__ float red[4][64];

    const int bh = blockIdx.x;
    const int c  = blockIdx.y;
    const int n  = bh >> 4, h = bh & 15;
    const int tid = threadIdx.x;
    const size_t rowbase = (size_t)n * LSEQ + (size_t)c * TCH;

    // vectorized staging: thread handles 4 rows x 4 cols; in-register 4x4
    // transpose (v_perm) so ALL LDS writes are b64.
    {
        const int t4 = tid >> 4;              // row group 0..15
        const int c0 = (tid & 15) * 4;        // col group
        uint2 ku[4], vu[4], qu[4];
        #pragma unroll
        for (int j = 0; j < 4; ++j) {
            size_t g = (rowbase + t4 * 4 + j) * DM + h * HD + c0;
            ku[j] = *(const uint2*)((const unsigned short*)kp + g);
            vu[j] = *(const uint2*)((const unsigned short*)v  + g);
            qu[j] = *(const uint2*)((const unsigned short*)qp + g);
        }
        #pragma unroll
        for (int j = 0; j < 4; ++j)
            *(uint2*)&qp_s[(t4 * 4 + j) * PS + c0] = qu[j];
        uint2 kc[4], vc[4];
        tr4x4(ku, kc);
        tr4x4(vu, vc);
        #pragma unroll
        for (int i = 0; i < 4; ++i) {
            *(uint2*)&kpT_s[(c0 + i) * PS + t4 * 4] = kc[i];
            *(uint2*)&vT_s [(c0 + i) * PS + t4 * 4] = vc[i];
        }
    }
    __syncthreads();

    const int wave = tid >> 6, lane = tid & 63;
    const int quad = lane >> 4, l16 = lane & 15;

    f32x4 acc[4] = {};
    #pragma unroll
    for (int kk = 0; kk < 2; ++kk) {
        bf16x8 af = *(const bf16x8*)&kpT_s[(wave*16 + l16) * PS + kk*32 + quad*8];
        #pragma unroll
        for (int ni = 0; ni < 4; ++ni) {
            bf16x8 bfr = *(const bf16x8*)&vT_s[(ni*16 + l16) * PS + kk*32 + quad*8];
            acc[ni] = __builtin_amdgcn_mfma_f32_16x16x32_bf16(af, bfr, acc[ni], 0, 0, 0);
        }
    }
    unsigned short* Sout = (unsigned short*)chunkSB + (((size_t)bh * NC + c) << 12);
    #pragma unroll
    for (int ni = 0; ni < 4; ++ni) {
        int k = ni*16 + l16;
        #pragma unroll
        for (int r = 0; r < 4; ++r) {
            int d = wave*16 + quad*4 + r;
            Sout[d * 64 + k] = f2u(acc[ni][r]);
        }
    }

    {
        int d = tid & 63, part = tid >> 6;
        float s = 0.f;
        #pragma unroll
        for (int t = part*16; t < part*16 + 16; ++t)
            s += u2f(qp_s[t * PS + d]);
        red[part][d] = s;
    }
    __syncthreads();
    if (tid < 64)
        chunkZ[((size_t)bh * NC + c) * 64 + tid] =
            red[0][tid] + red[1][tid] + red[2][tid] + red[3][tid];
}

// ---------------------------------------------------------------------------
// Pass 2: exclusive prefix over chunks (bf16 in, fp32 accumulate, bf16 out)
__global__ __launch_bounds__(256) void prefix_state(
    const bf16* __restrict__ chunkSB, bf16* __restrict__ SpB,
    float* __restrict__ chunkZ)
{
    const int bh = blockIdx.x;
    const int elem = blockIdx.y * 256 + threadIdx.x;   // 0..4095
    const unsigned short* p = (const unsigned short*)chunkSB + (((size_t)bh * NC) << 12) + elem;
    unsigned short* o = (unsigned short*)SpB + (((size_t)bh * NC) << 12) + elem;
    float run = 0.f;
    #pragma unroll
    for (int c = 0; c < NC; ++c) {
        float x = u2f(p[(size_t)c << 12]);
        o[(size_t)c << 12] = f2u(run);
        run += x;
    }
    if (blockIdx.y == 0 && threadIdx.x < 64) {
        float* pz = chunkZ + (size_t)bh * NC * 64 + threadIdx.x;
        float rz = 0.f;
        for (int c = 0; c < NC; ++c) {
            float x = pz[c * 64];
            pz[c * 64] = rz;
            rz += x;
        }
    }
}

// ---------------------------------------------------------------------------
// Pass 3 (MFMA): att = (qp@Sp + tril(qp@kp^T)@v) / (Zp + tril(1)@qp)
__global__ __launch_bounds__(256) void chunk_attn(
    const bf16* __restrict__ qp, const bf16* __restrict__ kp,
    const bf16* __restrict__ v, const bf16* __restrict__ SpB,
    const float* __restrict__ chunkZ, bf16* __restrict__ att)
{
    __shared__ __align__(16) unsigned short qp_s [64 * PS];
    __shared__ __align__(16) unsigned short kp_s [64 * PS];
    __shared__ __align__(16) unsigned short SpT_s[64 * PS];
    __shared__ __align__(16) unsigned short vT_s [64 * PS];
    __shared__ __align__(16) unsigned short qpT_s[64 * PS];
    __shared__ __align__(16) unsigned short P_s  [64 * PS];

    const int bh = blockIdx.x;
    const int c  = blockIdx.y;
    const int n  = bh >> 4, h = bh & 15;
    const int tid = threadIdx.x;
    const size_t rowbase = (size_t)n * LSEQ + (size_t)c * TCH;
    const unsigned short* Spb = (const unsigned short*)SpB + (((size_t)bh * NC + c) << 12);

    {
        const int t4 = tid >> 4;
        const int c0 = (tid & 15) * 4;
        uint2 qu[4], ku[4], vu[4], su[4];
        #pragma unroll
        for (int j = 0; j < 4; ++j) {
            size_t g = (rowbase + t4 * 4 + j) * DM + h * HD + c0;
            qu[j] = *(const uint2*)((const unsigned short*)qp + g);
            ku[j] = *(const uint2*)((const unsigned short*)kp + g);
            vu[j] = *(const uint2*)((const unsigned short*)v  + g);
            su[j] = *(const uint2*)(Spb + (t4 * 4 + j) * 64 + c0);
        }
        #pragma unroll
        for (int j = 0; j < 4; ++j) {
            *(uint2*)&qp_s[(t4 * 4 + j) * PS + c0] = qu[j];
            *(uint2*)&kp_s[(t4 * 4 + j) * PS + c0] = ku[j];
        }
        uint2 vc[4], qc[4], sc[4];
        tr4x4(vu, vc);
        tr4x4(qu, qc);
        tr4x4(su, sc);
        #pragma unroll
        for (int i = 0; i < 4; ++i) {
            *(uint2*)&vT_s [(c0 + i) * PS + t4 * 4] = vc[i];
            *(uint2*)&qpT_s[(c0 + i) * PS + t4 * 4] = qc[i];
            *(uint2*)&SpT_s[(c0 + i) * PS + t4 * 4] = sc[i];
        }
    }
    __syncthreads();

    const int wave = tid >> 6, lane = tid & 63;
    const int quad = lane >> 4, l16 = lane & 15;
    const int mrow = wave * 16;

    f32x4 acc[4]  = {};
    f32x4 zacc[4] = {};
    f32x4 pacc[4] = {};

    const unsigned short ONE = 0x3F80;

    #pragma unroll
    for (int kk = 0; kk < 2; ++kk) {
        bf16x8 af = *(const bf16x8*)&qp_s[(mrow + l16) * PS + kk*32 + quad*8];
        bf16x8 tf;
        #pragma unroll
        for (int j = 0; j < 8; ++j) {
            int s = kk*32 + quad*8 + j;
            tf[j] = (short)((s <= mrow + l16) ? ONE : 0);
        }
        #pragma unroll
        for (int ni = 0; ni < 4; ++ni) {
            int boff = (ni*16 + l16) * PS + kk*32 + quad*8;
            bf16x8 b_sp = *(const bf16x8*)&SpT_s[boff];
            bf16x8 b_kp = *(const bf16x8*)&kp_s [boff];
            bf16x8 b_qt = *(const bf16x8*)&qpT_s[boff];
            acc [ni] = __builtin_amdgcn_mfma_f32_16x16x32_bf16(af, b_sp, acc [ni], 0, 0, 0);
            pacc[ni] = __builtin_amdgcn_mfma_f32_16x16x32_bf16(af, b_kp, pacc[ni], 0, 0, 0);
            zacc[ni] = __builtin_amdgcn_mfma_f32_16x16x32_bf16(tf, b_qt, zacc[ni], 0, 0, 0);
        }
    }

    #pragma unroll
    for (int ni = 0; ni < 4; ++ni) {
        int s = ni*16 + l16;
        #pragma unroll
        for (int r = 0; r < 4; ++r) {
            int t = mrow + quad*4 + r;
            float pv = (s <= t) ? pacc[ni][r] : 0.f;
            P_s[t * PS + s] = f2u(pv);
        }
    }
    __syncthreads();

    #pragma unroll
    for (int kk = 0; kk < 2; ++kk) {
        bf16x8 af = *(const bf16x8*)&P_s[(mrow + l16) * PS + kk*32 + quad*8];
        #pragma unroll
        for (int ni = 0; ni < 4; ++ni) {
            bf16x8 b_v = *(const bf16x8*)&vT_s[(ni*16 + l16) * PS + kk*32 + quad*8];
            acc[ni] = __builtin_amdgcn_mfma_f32_16x16x32_bf16(af, b_v, acc[ni], 0, 0, 0);
        }
    }

    #pragma unroll
    for (int ni = 0; ni < 4; ++ni) {
        int k = ni*16 + l16;
        float zp = chunkZ[((size_t)bh * NC + c) * 64 + k];
        #pragma unroll
        for (int r = 0; r < 4; ++r) {
            int t = mrow + quad*4 + r;
            float o = acc[ni][r] / (zp + zacc[ni][r]);
            ((unsigned short*)att)[(rowbase + t) * DM + h * HD + k] = f2u(o);
        }
    }
}

// ---------------------------------------------------------------------------
extern "C" void kernel_launch(void* const* d_in, const int* in_sizes, int n_in,
                              void* d_out, int out_size, void* d_ws, size_t ws_size,
                              hipStream_t stream)
{
    const float* queries = (const float*)d_in[0];
    const float* keys    = (const float*)d_in[1];
    const float* values  = (const float*)d_in[2];
    const float* Wq = (const float*)d_in[3];
    const float* bq = (const float*)d_in[4];
    const float* Wk = (const float*)d_in[5];
    const float* bk = (const float*)d_in[6];
    const float* Wv = (const float*)d_in[7];
    const float* bv = (const float*)d_in[8];
    const float* Wo = (const float*)d_in[9];
    const float* bo = (const float*)d_in[10];
    float* out = (float*)d_out;

    char* w = (char*)d_ws;
    const size_t E2 = (size_t)MROWS * DM * 2;   // 16,777,216
    const size_t WB = (size_t)DM * DM * 2;      //  2,097,152
    bf16* qb  = (bf16*)(w + 0 * E2);            // reused as att
    bf16* kb  = (bf16*)(w + 1 * E2);            // reused as chunkSB (bf16)
    bf16* vb  = (bf16*)(w + 2 * E2);
    bf16* Wqt = (bf16*)(w + 3 * E2 + 0 * WB);   // reused as chunkZ
    bf16* Wkt = (bf16*)(w + 3 * E2 + 1 * WB);
    bf16* Wvt = (bf16*)(w + 3 * E2 + 2 * WB);
    bf16* Wot = (bf16*)(w + 3 * E2 + 3 * WB);
    bf16* qp  = (bf16*)(w + 3 * E2 + 4 * WB);
    bf16* kp  = (bf16*)(w + 4 * E2 + 4 * WB);
    bf16* vv  = (bf16*)(w + 5 * E2 + 4 * WB);
    bf16* SpB = (bf16*)(w + 6 * E2 + 4 * WB);
    bf16*  chunkSB = kb;
    float* chunkZ  = (float*)Wqt;
    bf16*  att     = qb;

    const int n4 = (MROWS * DM) / 4;    // 2,097,152
    const int per = n4 / 256;           // 8192 blocks per tensor
    cvt3_f32_bf16<<<3 * per, 256, 0, stream>>>(queries, keys, values, qb, kb, vb, per);

    transpose_w4<<<dim3(DM / 64, DM / 64, 4), 256, 0, stream>>>(
        Wq, Wk, Wv, Wo, Wqt, Wkt, Wvt, Wot);

    // 3 projection GEMMs fused: z=0 q (elu+1), z=1 k (elu+1), z=2 v (none)
    gemm_mfma3<bf16, 8><<<dim3(MROWS / 256, DM / 256, 3), 512, 0, stream>>>(
        qb, kb, vb, Wqt, Wkt, Wvt, bq, bk, bv, qp, kp, vv,
        0b011, MROWS, DM, DM);

    chunk_state <<<dim3(64, NC), 256, 0, stream>>>(qp, kp, vv, chunkSB, chunkZ);
    prefix_state<<<dim3(64, 16), 256, 0, stream>>>(chunkSB, SpB, chunkZ);
    chunk_attn  <<<dim3(64, NC), 256, 0, stream>>>(qp, kp, vv, SpB, chunkZ, att);

    // output GEMM: MF=4 (BM=128) -> 64x4 = 256 blocks = one clean round
    gemm_mfma3<float, 4><<<dim3(MROWS / 128, DM / 256, 1), 512, 0, stream>>>(
        att, att, att, Wot, Wot, Wot, bo, bo, bo, out, out, out,
        0, MROWS, DM, DM);
}